// Round 10
// baseline (61.533 us; speedup 1.0000x reference)
//
#include <hip/hip_runtime.h>
#include <hip/hip_bf16.h>

#define LOGK 11
#define K 2048
#define LMINF  -11.172813415527344f
#define RANGEF  25.154841423034668f   // LABEL_MAX - LABEL_MIN
#define GSCALE 65536.0
#define GSCALEF 65536.0f
#define GMASK  ((1ULL << 47) - 1)
#define LN2D   0.6931471805599453
#define X0     4096                   // exact disc-prefix below this rank
#define NB     512                    // histogram blocks: 2 per CU

// descending bucket of a float32 score via sortable-uint top bits
__device__ __forceinline__ unsigned bucket_out(float x) {
    unsigned u = __float_as_uint(x);
    unsigned key = u ^ ((u >> 31) ? 0xFFFFFFFFu : 0x80000000u);
    return (~key) >> (32 - LOGK);
}
// descending bucket of a label in [0,1)
__device__ __forceinline__ unsigned bucket_lab(float l) {
    unsigned u = (unsigned)(l * (float)K);
    if (u > (unsigned)(K - 1)) u = K - 1;
    return (unsigned)(K - 1) - u;
}

// ---------------------------------------------------------------------------
// P1: ONE pass builds BOTH histograms. 40 KB LDS, grid=512 -> 2 blocks/CU.
// Round-9 lesson (VGPR=28): guarded loads were SERIALIZED by the compiler —
// this version issues all 8 float4 loads unconditionally (indices clamped,
// item-processing guarded) so they batch into one 8-deep MLP group.
// pk copies are split by LANE parity (tid&1), not wave parity: same-address
// dup serialization happens within a wave's atomic execution, so the split
// must separate adjacent lanes.
//  pk[2][K] u64 packed: [63:47]=count, [46:0]=(gain+1)*2^16
//  cnt2[K]  u32 label counts (label-bucket mean gain is analytic).
// ---------------------------------------------------------------------------
#define ITEM(S, L)                                                              \
    {                                                                           \
        float h_ = exp2f(fmaf((L), RANGEF, LMINF)); /* gain+1 > 0 */            \
        unsigned gf_ = (unsigned)(h_ * GSCALEF);                                \
        atomicAdd(&mypk[bucket_out(S)], (1ULL << 47) | (unsigned long long)gf_);\
        atomicAdd(&cnt2[bucket_lab(L)], 1u);                                    \
    }

extern "C" __global__ __launch_bounds__(1024, 8)
void ndcg_hist7(const float* __restrict__ sc, const float* __restrict__ lb,
                unsigned* __restrict__ gc1, unsigned long long* __restrict__ gh1,
                unsigned* __restrict__ gc2, int n4) {
    __shared__ unsigned long long pk[2][K];  // 32 KB
    __shared__ unsigned cnt2[K];             // 8 KB
    const int rb  = blockIdx.x;
    const int tid = threadIdx.x;
    for (int c = tid; c < 2 * K; c += 1024) ((unsigned long long*)pk)[c] = 0ull;
    for (int c = tid; c < K; c += 1024) cnt2[c] = 0u;
    __syncthreads();
    unsigned long long* mypk = pk[tid & 1];
    const float4* sc4 = (const float4*)sc;
    const float4* lb4 = (const float4*)lb;
    const int col = NB << 10;                // float4s per column
    const int cap = n4 - 1;
    for (int i = rb * 1024 + tid; i < n4; i += 4 * col) {
        int i1 = min(i + col, cap), i2 = min(i + 2 * col, cap), i3 = min(i + 3 * col, cap);
        // ALL loads unconditional and independent -> one 8-deep batch
        float4 s0 = sc4[i],  s1 = sc4[i1], s2 = sc4[i2], s3 = sc4[i3];
        float4 l0 = lb4[i],  l1 = lb4[i1], l2 = lb4[i2], l3 = lb4[i3];
        bool h1 = i + col < n4, h2 = i + 2 * col < n4, h3 = i + 3 * col < n4;
        ITEM(s0.x, l0.x) ITEM(s0.y, l0.y) ITEM(s0.z, l0.z) ITEM(s0.w, l0.w)
        if (h1) { ITEM(s1.x, l1.x) ITEM(s1.y, l1.y) ITEM(s1.z, l1.z) ITEM(s1.w, l1.w) }
        if (h2) { ITEM(s2.x, l2.x) ITEM(s2.y, l2.y) ITEM(s2.z, l2.z) ITEM(s2.w, l2.w) }
        if (h3) { ITEM(s3.x, l3.x) ITEM(s3.y, l3.y) ITEM(s3.z, l3.z) ITEM(s3.w, l3.w) }
    }
    __syncthreads();
    for (int c = tid; c < K; c += 1024) {
        unsigned long long v = pk[0][c] + pk[1][c];   // fields can't overflow
        if (v) {
            atomicAdd(&gc1[c], (unsigned)(v >> 47));
            atomicAdd(&gh1[c], v & GMASK);
        }
        unsigned c2 = cnt2[c];
        if (c2) atomicAdd(&gc2[c], c2);
    }
}

// ---------------------------------------------------------------------------
// P2 (fused, single block): scan counts -> base ranks (LDS), exact f64
// disc-prefix Dex[0..X0] (LDS), analytic bucket contributions, reduce,
// out = dcg/zk.  S(x)=sum_{r<x} 1/log2(r+2): exact table below X0,
// Euler-Maclaurin + li(x) beyond. li is DIVISION-FREE (round-8 lesson:
// f64 divides on one block = 280us).
// ---------------------------------------------------------------------------
__device__ __forceinline__ double li_x(double x) {
    double lx = log(x);
    double term = 1.0, sum = 0.0;
#pragma unroll
    for (int k = 1; k <= 48; ++k) {
        term *= lx * (1.0 / (double)k);   // constants fold at compile time
        sum  += term * (1.0 / (double)k);
    }
    return 0.5772156649015329 + log(lx) + sum;
}

__device__ __forceinline__ double S_of(const double* Dex, unsigned x) {
    if (x <= (unsigned)X0) return Dex[x];
    double B = (double)x + 1.0;
    double lB = log(B);
    const double A = (double)(X0 + 2);
    double lA = log(A);                    // constant-folded
    double integral = li_x(B) - li_x(A);   // li_x(A) constant-folded
    double edge = 0.5 * (1.0 / lA + 1.0 / lB);
    double der  = (1.0 / (A * lA * lA) - 1.0 / (B * lB * lB)) * (1.0 / 12.0);
    return Dex[X0] + LN2D * (integral + edge + der);
}

extern "C" __global__ __launch_bounds__(1024)
void ndcg_post(const unsigned* __restrict__ gc1, const unsigned* __restrict__ gc2,
               const unsigned long long* __restrict__ gh1,
               float* __restrict__ out) {
    __shared__ unsigned base1[K + 1];        // 8 KB
    __shared__ unsigned base2[K + 1];        // 8 KB
    __shared__ double   Dex[X0 + 1];         // 32 KB
    __shared__ double   sd[1024];            // 8 KB scratch (u32 view for scans)
    unsigned* su = (unsigned*)sd;
    const int t = threadIdx.x;

    // --- phase A: exclusive scans (counts -> base ranks), 2/thread
#pragma unroll
    for (int tbl = 0; tbl < 2; ++tbl) {
        const unsigned* in   = tbl ? gc2 : gc1;
        unsigned*       outb = tbl ? base2 : base1;
        unsigned v0 = in[t * 2], v1 = in[t * 2 + 1];
        su[t] = v0 + v1;
        __syncthreads();
        for (int off = 1; off < 1024; off <<= 1) {
            unsigned add = (t >= off) ? su[t - off] : 0u;
            __syncthreads();
            su[t] += add;
            __syncthreads();
        }
        unsigned run = (t == 0) ? 0u : su[t - 1];
        outb[t * 2]     = run;  run += v0;
        outb[t * 2 + 1] = run;  run += v1;
        if (t == 1023) outb[K] = run;        // = n
        __syncthreads();
    }

    // --- phase B: exact disc-prefix Dex[0..X0], 4/thread
    double d0 = LN2D / log((double)(t * 4 + 2));
    double d1 = LN2D / log((double)(t * 4 + 3));
    double d2 = LN2D / log((double)(t * 4 + 4));
    double d3 = LN2D / log((double)(t * 4 + 5));
    sd[t] = d0 + d1 + d2 + d3;
    __syncthreads();
    for (int off = 1; off < 1024; off <<= 1) {
        double add = (t >= off) ? sd[t - off] : 0.0;
        __syncthreads();
        sd[t] += add;
        __syncthreads();
    }
    {
        double run = (t == 0) ? 0.0 : sd[t - 1];
        if (t == 0) Dex[0] = 0.0;
        run += d0; Dex[t * 4 + 1] = run;
        run += d1; Dex[t * 4 + 2] = run;
        run += d2; Dex[t * 4 + 3] = run;
        run += d3; Dex[t * 4 + 4] = run;
    }
    __syncthreads();

    // --- phase C: analytic bucket contributions (4 per thread)
    double ld = 0.0, lz = 0.0;
#pragma unroll
    for (int j = 0; j < 4; ++j) {
        int idx = t + j * 1024;              // [0, 2K)
        int table = idx >> LOGK;
        int c = idx & (K - 1);
        if (table == 0) {
            unsigned a = base1[c], e = base1[c + 1];
            if (e > a) {
                unsigned cnt = e - a;
                double gsum = (double)gh1[c] * (1.0 / GSCALE) - (double)cnt;
                ld += (gsum / (double)cnt) * (S_of(Dex, e) - S_of(Dex, a));
            }
        } else {
            unsigned a = base2[c], e = base2[c + 1];
            if (e > a) {
                float lc = ((float)(K - 1 - c) + 0.5f) * (1.0f / (float)K);
                double avg = (double)(exp2f(fmaf(lc, RANGEF, LMINF)) - 1.0f);
                lz += avg * (S_of(Dex, e) - S_of(Dex, a));
            }
        }
    }
    // --- phase D: block reduction, write result
    for (int off = 32; off > 0; off >>= 1) {
        ld += __shfl_down(ld, off, 64);
        lz += __shfl_down(lz, off, 64);
    }
    __syncthreads();                         // sd reuse
    int wid = t >> 6, lane = t & 63;
    if (lane == 0) { sd[wid] = ld; sd[16 + wid] = lz; }
    __syncthreads();
    if (t == 0) {
        double a0 = 0.0, b0 = 0.0;
#pragma unroll
        for (int w = 0; w < 16; ++w) { a0 += sd[w]; b0 += sd[16 + w]; }
        out[0] = (float)(a0 / b0);
    }
}

extern "C" void kernel_launch(void* const* d_in, const int* in_sizes, int n_in,
                              void* d_out, int out_size, void* d_ws, size_t ws_size,
                              hipStream_t stream) {
    const float* sc = (const float*)d_in[0];
    const float* lb = (const float*)d_in[1];
    int n = in_sizes[0];
    int n4 = n / 4;

    // workspace layout (gh1,gc1,gc2 contiguous for one memset)
    char* p = (char*)d_ws;
    size_t off = 0;
    unsigned long long* gh1 = (unsigned long long*)(p + off); off += (size_t)K * 8;
    unsigned*           gc1 = (unsigned*)(p + off);           off += (size_t)K * 4;
    unsigned*           gc2 = (unsigned*)(p + off);           off += (size_t)K * 4;

    hipMemsetAsync(gh1, 0, (size_t)K * 16, stream);   // gh1 + gc1 + gc2

    ndcg_hist7<<<dim3(NB), dim3(1024), 0, stream>>>(sc, lb, gc1, gh1, gc2, n4);
    ndcg_post<<<dim3(1), dim3(1024), 0, stream>>>(gc1, gc2, gh1, (float*)d_out);
}

// Round 11
// 58.452 us; speedup vs baseline: 1.0527x; 1.0527x over previous
//
#include <hip/hip_runtime.h>
#include <hip/hip_bf16.h>

#define LOGK 11
#define K 2048
#define LMINF  -11.172813415527344f
#define RANGEF  25.154841423034668f   // LABEL_MAX - LABEL_MIN
#define GSCALE 65536.0
#define GSCALEF 65536.0f
#define GMASK  ((1ULL << 47) - 1)
#define LN2D   0.6931471805599453
#define X0     4096                   // exact disc-prefix below this rank
#define NB     512                    // histogram blocks: 2 per CU

// descending bucket of a float32 score via sortable-uint top bits
__device__ __forceinline__ unsigned bucket_out(float x) {
    unsigned u = __float_as_uint(x);
    unsigned key = u ^ ((u >> 31) ? 0xFFFFFFFFu : 0x80000000u);
    return (~key) >> (32 - LOGK);
}
// descending bucket of a label in [0,1)
__device__ __forceinline__ unsigned bucket_lab(float l) {
    unsigned u = (unsigned)(l * (float)K);
    if (u > (unsigned)(K - 1)) u = K - 1;
    return (unsigned)(K - 1) - u;
}

// ---------------------------------------------------------------------------
// P1: ONE pass builds BOTH histograms. 40 KB LDS, grid=512 -> 2 blocks/CU.
// Round-10 lesson (VGPR stuck at 28): the compiler SINKS loads to their
// uses, killing memory-level parallelism. This version is an explicit
// 2-stage software pipeline: issue next stage's 4 float4 loads, then
// __builtin_amdgcn_sched_barrier(0) pins them BEFORE the current stage's
// LDS-atomic block, so atomics execute with 4 loads in flight.
//  pk[2][K] u64 packed: [63:47]=count, [46:0]=(gain+1)*2^16
//  cnt2[K]  u32 label counts (label-bucket mean gain is analytic).
// (Conflict note: SQ_LDS_BANK_CONFLICT ~3.5M is invariant to K and pk
//  layout across rounds 6-10 — inherent to value distribution; ignore.)
// ---------------------------------------------------------------------------
#define ITEM(S, L)                                                              \
    {                                                                           \
        float h_ = exp2f(fmaf((L), RANGEF, LMINF)); /* gain+1 > 0 */            \
        unsigned gf_ = (unsigned)(h_ * GSCALEF);                                \
        atomicAdd(&mypk[bucket_out(S)], (1ULL << 47) | (unsigned long long)gf_);\
        atomicAdd(&cnt2[bucket_lab(L)], 1u);                                    \
    }
#define ITEM4(S4, L4)                                                           \
    ITEM((S4).x, (L4).x) ITEM((S4).y, (L4).y)                                   \
    ITEM((S4).z, (L4).z) ITEM((S4).w, (L4).w)

extern "C" __global__ __launch_bounds__(1024, 8)
void ndcg_hist8(const float* __restrict__ sc, const float* __restrict__ lb,
                unsigned* __restrict__ gc1, unsigned long long* __restrict__ gh1,
                unsigned* __restrict__ gc2, int n4) {
    __shared__ unsigned long long pk[2][K];  // 32 KB
    __shared__ unsigned cnt2[K];             // 8 KB
    const int tid = threadIdx.x;
    for (int c = tid; c < 2 * K; c += 1024) ((unsigned long long*)pk)[c] = 0ull;
    for (int c = tid; c < K; c += 1024) cnt2[c] = 0u;
    __syncthreads();
    unsigned long long* mypk = pk[tid & 1];
    const float4* sc4 = (const float4*)sc;
    const float4* lb4 = (const float4*)lb;
    const int st = NB << 10;                 // float4 stride between chunks
    int i0 = blockIdx.x * 1024 + tid;

    // pipelined groups of 8 chunks (exactly one group for n=16.7M)
    while (i0 + 7 * st < n4) {
        float4 as0 = sc4[i0],      al0 = lb4[i0];
        float4 as1 = sc4[i0 + st], al1 = lb4[i0 + st];
#pragma unroll
        for (int k = 0; k < 3; ++k) {
            int j = i0 + (2 * k + 2) * st;
            float4 bs0 = sc4[j],      bl0 = lb4[j];
            float4 bs1 = sc4[j + st], bl1 = lb4[j + st];
            __builtin_amdgcn_sched_barrier(0);   // loads stay ABOVE the atomics
            ITEM4(as0, al0) ITEM4(as1, al1)
            as0 = bs0; al0 = bl0; as1 = bs1; al1 = bl1;
        }
        ITEM4(as0, al0) ITEM4(as1, al1)
        i0 += 8 * st;
    }
    // guarded tail (empty when n4 % (8*st) == 0)
    for (int i = i0; i < n4; i += st) {
        float4 s = sc4[i], l = lb4[i];
        ITEM4(s, l)
    }

    __syncthreads();
    for (int c = tid; c < K; c += 1024) {
        unsigned long long v = pk[0][c] + pk[1][c];   // fields can't overflow
        if (v) {
            atomicAdd(&gc1[c], (unsigned)(v >> 47));
            atomicAdd(&gh1[c], v & GMASK);
        }
        unsigned c2 = cnt2[c];
        if (c2) atomicAdd(&gc2[c], c2);
    }
}

// ---------------------------------------------------------------------------
// P2 (fused, single block): scan counts -> base ranks (LDS), exact f64
// disc-prefix Dex[0..X0] (LDS), analytic bucket contributions, reduce,
// out = dcg/zk.  S(x)=sum_{r<x} 1/log2(r+2): exact table below X0,
// Euler-Maclaurin + li(x) beyond. li is DIVISION-FREE (round-8 lesson:
// f64 divides on one block = 280us).
// ---------------------------------------------------------------------------
__device__ __forceinline__ double li_x(double x) {
    double lx = log(x);
    double term = 1.0, sum = 0.0;
#pragma unroll
    for (int k = 1; k <= 48; ++k) {
        term *= lx * (1.0 / (double)k);   // constants fold at compile time
        sum  += term * (1.0 / (double)k);
    }
    return 0.5772156649015329 + log(lx) + sum;
}

__device__ __forceinline__ double S_of(const double* Dex, unsigned x) {
    if (x <= (unsigned)X0) return Dex[x];
    double B = (double)x + 1.0;
    double lB = log(B);
    const double A = (double)(X0 + 2);
    double lA = log(A);                    // constant-folded
    double integral = li_x(B) - li_x(A);   // li_x(A) constant-folded
    double edge = 0.5 * (1.0 / lA + 1.0 / lB);
    double der  = (1.0 / (A * lA * lA) - 1.0 / (B * lB * lB)) * (1.0 / 12.0);
    return Dex[X0] + LN2D * (integral + edge + der);
}

extern "C" __global__ __launch_bounds__(1024)
void ndcg_post(const unsigned* __restrict__ gc1, const unsigned* __restrict__ gc2,
               const unsigned long long* __restrict__ gh1,
               float* __restrict__ out) {
    __shared__ unsigned base1[K + 1];        // 8 KB
    __shared__ unsigned base2[K + 1];        // 8 KB
    __shared__ double   Dex[X0 + 1];         // 32 KB
    __shared__ double   sd[1024];            // 8 KB scratch (u32 view for scans)
    unsigned* su = (unsigned*)sd;
    const int t = threadIdx.x;

    // --- phase A: exclusive scans (counts -> base ranks), 2/thread
#pragma unroll
    for (int tbl = 0; tbl < 2; ++tbl) {
        const unsigned* in   = tbl ? gc2 : gc1;
        unsigned*       outb = tbl ? base2 : base1;
        unsigned v0 = in[t * 2], v1 = in[t * 2 + 1];
        su[t] = v0 + v1;
        __syncthreads();
        for (int off = 1; off < 1024; off <<= 1) {
            unsigned add = (t >= off) ? su[t - off] : 0u;
            __syncthreads();
            su[t] += add;
            __syncthreads();
        }
        unsigned run = (t == 0) ? 0u : su[t - 1];
        outb[t * 2]     = run;  run += v0;
        outb[t * 2 + 1] = run;  run += v1;
        if (t == 1023) outb[K] = run;        // = n
        __syncthreads();
    }

    // --- phase B: exact disc-prefix Dex[0..X0], 4/thread
    double d0 = LN2D / log((double)(t * 4 + 2));
    double d1 = LN2D / log((double)(t * 4 + 3));
    double d2 = LN2D / log((double)(t * 4 + 4));
    double d3 = LN2D / log((double)(t * 4 + 5));
    sd[t] = d0 + d1 + d2 + d3;
    __syncthreads();
    for (int off = 1; off < 1024; off <<= 1) {
        double add = (t >= off) ? sd[t - off] : 0.0;
        __syncthreads();
        sd[t] += add;
        __syncthreads();
    }
    {
        double run = (t == 0) ? 0.0 : sd[t - 1];
        if (t == 0) Dex[0] = 0.0;
        run += d0; Dex[t * 4 + 1] = run;
        run += d1; Dex[t * 4 + 2] = run;
        run += d2; Dex[t * 4 + 3] = run;
        run += d3; Dex[t * 4 + 4] = run;
    }
    __syncthreads();

    // --- phase C: analytic bucket contributions (4 per thread)
    double ld = 0.0, lz = 0.0;
#pragma unroll
    for (int j = 0; j < 4; ++j) {
        int idx = t + j * 1024;              // [0, 2K)
        int table = idx >> LOGK;
        int c = idx & (K - 1);
        if (table == 0) {
            unsigned a = base1[c], e = base1[c + 1];
            if (e > a) {
                unsigned cnt = e - a;
                double gsum = (double)gh1[c] * (1.0 / GSCALE) - (double)cnt;
                ld += (gsum / (double)cnt) * (S_of(Dex, e) - S_of(Dex, a));
            }
        } else {
            unsigned a = base2[c], e = base2[c + 1];
            if (e > a) {
                float lc = ((float)(K - 1 - c) + 0.5f) * (1.0f / (float)K);
                double avg = (double)(exp2f(fmaf(lc, RANGEF, LMINF)) - 1.0f);
                lz += avg * (S_of(Dex, e) - S_of(Dex, a));
            }
        }
    }
    // --- phase D: block reduction, write result
    for (int off = 32; off > 0; off >>= 1) {
        ld += __shfl_down(ld, off, 64);
        lz += __shfl_down(lz, off, 64);
    }
    __syncthreads();                         // sd reuse
    int wid = t >> 6, lane = t & 63;
    if (lane == 0) { sd[wid] = ld; sd[16 + wid] = lz; }
    __syncthreads();
    if (t == 0) {
        double a0 = 0.0, b0 = 0.0;
#pragma unroll
        for (int w = 0; w < 16; ++w) { a0 += sd[w]; b0 += sd[16 + w]; }
        out[0] = (float)(a0 / b0);
    }
}

extern "C" void kernel_launch(void* const* d_in, const int* in_sizes, int n_in,
                              void* d_out, int out_size, void* d_ws, size_t ws_size,
                              hipStream_t stream) {
    const float* sc = (const float*)d_in[0];
    const float* lb = (const float*)d_in[1];
    int n = in_sizes[0];
    int n4 = n / 4;

    // workspace layout (gh1,gc1,gc2 contiguous for one memset)
    char* p = (char*)d_ws;
    size_t off = 0;
    unsigned long long* gh1 = (unsigned long long*)(p + off); off += (size_t)K * 8;
    unsigned*           gc1 = (unsigned*)(p + off);           off += (size_t)K * 4;
    unsigned*           gc2 = (unsigned*)(p + off);           off += (size_t)K * 4;

    hipMemsetAsync(gh1, 0, (size_t)K * 16, stream);   // gh1 + gc1 + gc2

    ndcg_hist8<<<dim3(NB), dim3(1024), 0, stream>>>(sc, lb, gc1, gh1, gc2, n4);
    ndcg_post<<<dim3(1), dim3(1024), 0, stream>>>(gc1, gc2, gh1, (float*)d_out);
}